// Round 12
// baseline (559.771 us; speedup 1.0000x reference)
//
#include <hip/hip_runtime.h>
#include <hip/hip_bf16.h>

#define C 128
#define RBFD 20
#define NATOMS 50000
#define SCAN_CHUNK 1024
#define SLAB 64           // edges per gather wave; 800000 % 64 == 0
#define PD 8              // pipeline depth (batches in flight); 64 % PD == 0

// ---------------------------------------------------------------------------
// Kernel 1: setup — transpose W1, W2 into [in][out], zero histogram counters,
// zero the accumulator (needed: boundary atomics + atoms with zero edges).
// ---------------------------------------------------------------------------
__global__ __launch_bounds__(256) void setup_kernel(
    const float* __restrict__ W1, const float* __restrict__ W2,
    float* __restrict__ W1T, float* __restrict__ W2T,
    int* __restrict__ count, float4* __restrict__ acc4,
    int n, int acc_quads)
{
    const int t = blockIdx.x * blockDim.x + threadIdx.x;
    const int stride = gridDim.x * blockDim.x;
    if (t < C * C) {
        int k = t / C;   // in-channel
        int c = t % C;   // out-channel
        W1T[t] = W1[c * C + k];
        W2T[t] = W2[c * C + k];
    }
    for (int i = t; i < n; i += stride) count[i] = 0;
    const float4 z = make_float4(0.f, 0.f, 0.f, 0.f);
    for (int i = t; i < acc_quads; i += stride) acc4[i] = z;
}

// ---------------------------------------------------------------------------
// CSR construction: histogram -> hierarchical exclusive scan -> perm fill
// ---------------------------------------------------------------------------
__global__ __launch_bounds__(256) void histogram_kernel(
    const int* __restrict__ idx, int* __restrict__ count, int E)
{
    int e = blockIdx.x * blockDim.x + threadIdx.x;
    if (e < E) atomicAdd(&count[idx[e]], 1);
}

__global__ __launch_bounds__(256) void scan_partials_kernel(
    const int* __restrict__ count, int* __restrict__ partial, int n)
{
    __shared__ int sm[256];
    const int start = blockIdx.x * SCAN_CHUNK;
    int s = 0;
    for (int i = threadIdx.x; i < SCAN_CHUNK; i += 256) {
        int g = start + i;
        if (g < n) s += count[g];
    }
    sm[threadIdx.x] = s;
    __syncthreads();
    for (int off = 128; off > 0; off >>= 1) {
        if (threadIdx.x < off) sm[threadIdx.x] += sm[threadIdx.x + off];
        __syncthreads();
    }
    if (threadIdx.x == 0) partial[blockIdx.x] = sm[0];
}

__global__ void scan_chunkbase_kernel(int* __restrict__ partial,
                                      int* __restrict__ base,
                                      int nchunks, int n)
{
    if (threadIdx.x == 0 && blockIdx.x == 0) {
        int run = 0;
        for (int k = 0; k < nchunks; ++k) {
            int t = partial[k];
            partial[k] = run;
            run += t;
        }
        base[n] = run;
    }
}

__global__ __launch_bounds__(1024) void scan_apply_kernel(
    const int* __restrict__ count, const int* __restrict__ chunk_base,
    int* __restrict__ base, int* __restrict__ cursor, int n)
{
    __shared__ int sm[SCAN_CHUNK];
    const int t = threadIdx.x;
    const int i = blockIdx.x * SCAN_CHUNK + t;
    int v = (i < n) ? count[i] : 0;
    sm[t] = v;
    __syncthreads();
    for (int off = 1; off < SCAN_CHUNK; off <<= 1) {
        int tmp = (t >= off) ? sm[t - off] : 0;
        __syncthreads();
        sm[t] += tmp;
        __syncthreads();
    }
    if (i < n) {
        int excl = sm[t] - v + chunk_base[blockIdx.x];
        base[i] = excl;
        cursor[i] = excl;
    }
}

// also records the owner atom of each perm slot (sequential-read later)
__global__ __launch_bounds__(256) void fill_perm_kernel(
    const int* __restrict__ idx, int* __restrict__ cursor,
    int* __restrict__ perm, int* __restrict__ own, int E)
{
    int e = blockIdx.x * blockDim.x + threadIdx.x;
    if (e < E) {
        int a = idx[e];
        int pos = atomicAdd(&cursor[a], 1);
        perm[pos] = e;
        own[pos] = a;
    }
}

// ---------------------------------------------------------------------------
// Gather kernel v9: single-wave blocks + INLINE-ASM load pipeline with
// counted vmcnt (AITER/HK pattern).
//  * Block = 64 threads = one wave = 64 channels; grid = (E/64) x 2 halves.
//  * Per edge, a rigid 6-load batch: 5x global_load_dwordx4 (rbf row, via
//    offset:N) + 1x global_load_dword (x).  All loads inline-asm, so the
//    compiler CANNOT insert conservative waits; we wait s_waitcnt vmcnt(42)
//    = (PD-1)*6, keeping 7 batches (2.7 KB/wave) in flight at all times.
//  * sched_barrier(0) after each waitcnt (rule: compiler hoists register
//    consumers past inline-asm waitcnt otherwise).
//  * Compiler-owned global loads (w, bias) are force-completed before the
//    pipeline via an empty-asm use pin, so vmcnt belongs to our asm alone
//    (flush stores/atomics add only rare, conservative extra waits).
//  * Segmented flush-on-owner-change as before; atomics only at boundaries.
// ---------------------------------------------------------------------------
struct R5 { float4 a, b, c, d, e; };

#define GL_BATCH(slot, eidx)                                                   \
    do {                                                                       \
        const int e_ = (eidx);                                                 \
        const float* rp_ = rbf + (size_t)e_ * RBFD;                            \
        const float* xq_ = x + ((size_t)e_ << 7) + ch;                         \
        asm volatile("global_load_dwordx4 %0, %1, off"                         \
                     : "=v"(pr[slot].a) : "v"(rp_));                           \
        asm volatile("global_load_dwordx4 %0, %1, off offset:16"               \
                     : "=v"(pr[slot].b) : "v"(rp_));                           \
        asm volatile("global_load_dwordx4 %0, %1, off offset:32"               \
                     : "=v"(pr[slot].c) : "v"(rp_));                           \
        asm volatile("global_load_dwordx4 %0, %1, off offset:48"               \
                     : "=v"(pr[slot].d) : "v"(rp_));                           \
        asm volatile("global_load_dwordx4 %0, %1, off offset:64"               \
                     : "=v"(pr[slot].e) : "v"(rp_));                           \
        asm volatile("global_load_dword %0, %1, off"                           \
                     : "=v"(px[slot]) : "v"(xq_));                             \
    } while (0)

__device__ __forceinline__ float dot20(const R5& p, const float* __restrict__ w,
                                       float bias) {
    float f = bias;
    f = fmaf(p.a.x, w[0],  f); f = fmaf(p.a.y, w[1],  f);
    f = fmaf(p.a.z, w[2],  f); f = fmaf(p.a.w, w[3],  f);
    f = fmaf(p.b.x, w[4],  f); f = fmaf(p.b.y, w[5],  f);
    f = fmaf(p.b.z, w[6],  f); f = fmaf(p.b.w, w[7],  f);
    f = fmaf(p.c.x, w[8],  f); f = fmaf(p.c.y, w[9],  f);
    f = fmaf(p.c.z, w[10], f); f = fmaf(p.c.w, w[11], f);
    f = fmaf(p.d.x, w[12], f); f = fmaf(p.d.y, w[13], f);
    f = fmaf(p.d.z, w[14], f); f = fmaf(p.d.w, w[15], f);
    f = fmaf(p.e.x, w[16], f); f = fmaf(p.e.y, w[17], f);
    f = fmaf(p.e.z, w[18], f); f = fmaf(p.e.w, w[19], f);
    return f;
}

__global__ __launch_bounds__(64, 2) void gather_kernel(
    const float* __restrict__ x,       // [E][C]
    const float* __restrict__ rbf,     // [E][RBFD]
    const float* __restrict__ env,     // [E]
    const int*   __restrict__ perm,    // [E]
    const int*   __restrict__ own,     // [E]
    const float* __restrict__ Wrbf,    // [C][RBFD]
    const float* __restrict__ brbf,    // [C]
    float* __restrict__ acc)           // [N][C] (pre-zeroed)
{
    __shared__ int  e_s[SLAB];
    __shared__ int2 oe_s[SLAB];        // .x = owner atom, .y = env bits

    const int tid  = threadIdx.x;      // 0..63
    const int bid  = blockIdx.x;
    const int slab = bid >> 1;
    const int ch   = ((bid & 1) << 6) | tid;   // channel 0..127
    const int p0   = slab << 6;

    {
        const int e = perm[p0 + tid];
        e_s[tid]  = e;
        oe_s[tid] = make_int2(own[p0 + tid], __float_as_int(env[e]));
    }

    float w[RBFD];
#pragma unroll
    for (int r = 0; r < RBFD; ++r) w[r] = Wrbf[ch * RBFD + r];
    const float bias = brbf[ch];

    __syncthreads();

    // Pin: force the compiler's own global loads (w, bias) to complete HERE,
    // so no compiler waitcnt lands inside the pipelined loop.
    asm volatile("" ::
        "v"(w[0]), "v"(w[1]), "v"(w[2]), "v"(w[3]), "v"(w[4]),
        "v"(w[5]), "v"(w[6]), "v"(w[7]), "v"(w[8]), "v"(w[9]),
        "v"(w[10]), "v"(w[11]), "v"(w[12]), "v"(w[13]), "v"(w[14]),
        "v"(w[15]), "v"(w[16]), "v"(w[17]), "v"(w[18]), "v"(w[19]),
        "v"(bias));

    const int first_own = oe_s[0].x;
    int   cur_own = first_own;
    float sum = 0.0f;

#define FLUSH()                                                                \
    do {                                                                       \
        if (cur_own == first_own)                                              \
            unsafeAtomicAdd(&acc[(size_t)cur_own * C + ch], sum);              \
        else acc[(size_t)cur_own * C + ch] = sum;                              \
    } while (0)

    R5    pr[PD];
    float px[PD];

    // ---- prologue: fill the pipeline (PD batches = 48 loads in flight) ----
#pragma unroll
    for (int i = 0; i < PD; ++i) GL_BATCH(i, e_s[i]);

    // ---- main loop: 8 outer x 8 unrolled inner; slot index compile-time ----
#pragma unroll 1
    for (int jo = 0; jo < SLAB; jo += PD) {
#pragma unroll
        for (int k = 0; k < PD; ++k) {
            // wait for the oldest batch only: (PD-1)*6 = 42 stay outstanding
            asm volatile("s_waitcnt vmcnt(42)" ::: "memory");
            __builtin_amdgcn_sched_barrier(0);

            const int2 m = oe_s[jo + k];
            const float f = dot20(pr[k], w, bias);
            const float v = f * __int_as_float(m.y) * px[k];

            if (m.x != cur_own) { FLUSH(); sum = 0.0f; cur_own = m.x; }
            sum += v;

            // refill this slot with batch (jo+k+PD); wrap in the epilogue so
            // the 6-loads-per-iteration vmcnt invariant never breaks.
            GL_BATCH(k, e_s[(jo + k + PD) & (SLAB - 1)]);
        }
    }
    // final flush: cur_own may span into the next slab -> atomic
    unsafeAtomicAdd(&acc[(size_t)cur_own * C + ch], sum);
#undef FLUSH
}

// ---------------------------------------------------------------------------
// Fused MLP head (unchanged).
// ---------------------------------------------------------------------------
__device__ __forceinline__ float silu_f(float v) {
    return v * (1.0f / (1.0f + __expf(-v)));
}

__global__ __launch_bounds__(256) void mlp_head_kernel(
    const float* __restrict__ acc,   // [N][C]
    const float* __restrict__ W1T,   // [C][C]  (k-major)
    const float* __restrict__ b1,    // [C]
    const float* __restrict__ W2T,   // [C][C]
    const float* __restrict__ b2,    // [C]
    const float* __restrict__ W3,    // [1][C]
    const float* __restrict__ b3,    // [1]
    float* __restrict__ out,         // [N]
    int natoms)
{
    __shared__ float As[C][C + 1];

    const int tid = threadIdx.x;
    const int a0  = blockIdx.x * C;
    const int tc  = tid & 15;
    const int ta  = tid >> 4;
    const int abase = ta * 8;
    const int cbase = tc * 8;

    {
        const int sub = tid >> 7;
        const int k   = tid & 127;
        for (int pair = 0; pair < 64; ++pair) {
            const int al = pair * 2 + sub;
            const int a  = a0 + al;
            float v = (a < natoms) ? acc[(size_t)a * C + k] : 0.0f;
            As[k][al] = v;
        }
    }
    __syncthreads();

    float r[8][8];

    // layer 1
#pragma unroll
    for (int i = 0; i < 8; ++i)
#pragma unroll
        for (int j = 0; j < 8; ++j) r[i][j] = 0.0f;

#pragma unroll 2
    for (int k = 0; k < C; ++k) {
        float4 bq0 = *reinterpret_cast<const float4*>(W1T + k * C + cbase);
        float4 bq1 = *reinterpret_cast<const float4*>(W1T + k * C + cbase + 4);
        float bv[8] = {bq0.x, bq0.y, bq0.z, bq0.w, bq1.x, bq1.y, bq1.z, bq1.w};
        float av[8];
#pragma unroll
        for (int i = 0; i < 8; ++i) av[i] = As[k][abase + i];
#pragma unroll
        for (int i = 0; i < 8; ++i)
#pragma unroll
            for (int j = 0; j < 8; ++j) r[i][j] = fmaf(av[i], bv[j], r[i][j]);
    }

    __syncthreads();
    {
        float bb[8];
#pragma unroll
        for (int j = 0; j < 8; ++j) bb[j] = b1[cbase + j];
#pragma unroll
        for (int i = 0; i < 8; ++i)
#pragma unroll
            for (int j = 0; j < 8; ++j)
                As[cbase + j][abase + i] = silu_f(r[i][j] + bb[j]);
    }
    __syncthreads();

    // layer 2
#pragma unroll
    for (int i = 0; i < 8; ++i)
#pragma unroll
        for (int j = 0; j < 8; ++j) r[i][j] = 0.0f;

#pragma unroll 2
    for (int k = 0; k < C; ++k) {
        float4 bq0 = *reinterpret_cast<const float4*>(W2T + k * C + cbase);
        float4 bq1 = *reinterpret_cast<const float4*>(W2T + k * C + cbase + 4);
        float bv[8] = {bq0.x, bq0.y, bq0.z, bq0.w, bq1.x, bq1.y, bq1.z, bq1.w};
        float av[8];
#pragma unroll
        for (int i = 0; i < 8; ++i) av[i] = As[k][abase + i];
#pragma unroll
        for (int i = 0; i < 8; ++i)
#pragma unroll
            for (int j = 0; j < 8; ++j) r[i][j] = fmaf(av[i], bv[j], r[i][j]);
    }

    __syncthreads();

    // final: silu(.. + b2) . W3
    {
        float bb[8], w3v[8];
#pragma unroll
        for (int j = 0; j < 8; ++j) bb[j] = b2[cbase + j];
        float4 wq0 = *reinterpret_cast<const float4*>(W3 + cbase);
        float4 wq1 = *reinterpret_cast<const float4*>(W3 + cbase + 4);
        w3v[0]=wq0.x; w3v[1]=wq0.y; w3v[2]=wq0.z; w3v[3]=wq0.w;
        w3v[4]=wq1.x; w3v[5]=wq1.y; w3v[6]=wq1.z; w3v[7]=wq1.w;

#pragma unroll
        for (int i = 0; i < 8; ++i) {
            float p = 0.0f;
#pragma unroll
            for (int j = 0; j < 8; ++j)
                p = fmaf(silu_f(r[i][j] + bb[j]), w3v[j], p);
            As[abase + i][tc] = p;
        }
    }
    __syncthreads();

    if (tid < C) {
        const int a = a0 + tid;
        if (a < natoms) {
            float s = 0.0f;
#pragma unroll
            for (int t = 0; t < 16; ++t) s += As[tid][t];
            out[a] = s + b3[0];
        }
    }
}

// ---------------------------------------------------------------------------
extern "C" void kernel_launch(void* const* d_in, const int* in_sizes, int n_in,
                              void* d_out, int out_size, void* d_ws, size_t ws_size,
                              hipStream_t stream) {
    const float* x      = (const float*)d_in[0];
    const float* rbf    = (const float*)d_in[1];
    const float* env    = (const float*)d_in[2];
    const int*   idx    = (const int*)  d_in[3];
    const float* Wrbf   = (const float*)d_in[5];
    const float* brbf   = (const float*)d_in[6];
    const float* W1     = (const float*)d_in[7];
    const float* b1     = (const float*)d_in[8];
    const float* W2     = (const float*)d_in[9];
    const float* b2     = (const float*)d_in[10];
    const float* W3     = (const float*)d_in[11];
    const float* b3     = (const float*)d_in[12];
    float*       out    = (float*)d_out;

    const int E = in_sizes[0] / C;        // 800000
    const int N = NATOMS;                 // 50000
    const int nchunks = (N + SCAN_CHUNK - 1) / SCAN_CHUNK;   // 49

    // workspace layout
    float* acc     = (float*)d_ws;                    // N*C
    float* W1T     = acc + (size_t)N * C;             // C*C
    float* W2T     = W1T + C * C;                     // C*C
    int*   count   = (int*)(W2T + C * C);             // N
    int*   base    = count + N;                       // N+1
    int*   cursor  = base + (N + 1);                  // N
    int*   partial = cursor + N;                      // 64
    int*   perm    = partial + 64;                    // E
    int*   own     = perm + E;                        // E

    // setup: transpose weights + zero counters + zero acc
    setup_kernel<<<2048, 256, 0, stream>>>(W1, W2, W1T, W2T, count,
                                           (float4*)acc, N, (N * C) / 4);

    histogram_kernel<<<(E + 255) / 256, 256, 0, stream>>>(idx, count, E);
    scan_partials_kernel<<<nchunks, 256, 0, stream>>>(count, partial, N);
    scan_chunkbase_kernel<<<1, 64, 0, stream>>>(partial, base, nchunks, N);
    scan_apply_kernel<<<nchunks, SCAN_CHUNK, 0, stream>>>(count, partial, base, cursor, N);
    fill_perm_kernel<<<(E + 255) / 256, 256, 0, stream>>>(idx, cursor, perm, own, E);

    // gather: one 64-thread (single-wave) block per (64-edge, 64-channel) tile
    gather_kernel<<<(E / SLAB) * 2, 64, 0, stream>>>(x, rbf, env, perm, own,
                                                     Wrbf, brbf, acc);

    const int tiles = (N + C - 1) / C;
    mlp_head_kernel<<<tiles, 256, 0, stream>>>(acc, W1T, b1, W2T, b2, W3, b3, out, N);
}

// Round 13
// 331.052 us; speedup vs baseline: 1.6909x; 1.6909x over previous
//
#include <hip/hip_runtime.h>
#include <hip/hip_bf16.h>

#define C 128
#define RBFD 20
#define NATOMS 50000
#define SCAN_CHUNK 1024
#define SLAB 128          // edges per gather block; 800000 % 128 == 0
#define SS 32             // sub-slab size (edges per pipeline stage)
#define NSS (SLAB / SS)   // 4 sub-slabs per slab

// ---------------------------------------------------------------------------
// Kernel 1: setup — transpose W1, W2 into [in][out], zero histogram counters,
// zero the accumulator (needed: boundary atomics + atoms with zero edges).
// ---------------------------------------------------------------------------
__global__ __launch_bounds__(256) void setup_kernel(
    const float* __restrict__ W1, const float* __restrict__ W2,
    float* __restrict__ W1T, float* __restrict__ W2T,
    int* __restrict__ count, float4* __restrict__ acc4,
    int n, int acc_quads)
{
    const int t = blockIdx.x * blockDim.x + threadIdx.x;
    const int stride = gridDim.x * blockDim.x;
    if (t < C * C) {
        int k = t / C;   // in-channel
        int c = t % C;   // out-channel
        W1T[t] = W1[c * C + k];
        W2T[t] = W2[c * C + k];
    }
    for (int i = t; i < n; i += stride) count[i] = 0;
    const float4 z = make_float4(0.f, 0.f, 0.f, 0.f);
    for (int i = t; i < acc_quads; i += stride) acc4[i] = z;
}

// ---------------------------------------------------------------------------
// CSR construction: histogram -> hierarchical exclusive scan -> perm fill
// ---------------------------------------------------------------------------
__global__ __launch_bounds__(256) void histogram_kernel(
    const int* __restrict__ idx, int* __restrict__ count, int E)
{
    int e = blockIdx.x * blockDim.x + threadIdx.x;
    if (e < E) atomicAdd(&count[idx[e]], 1);
}

__global__ __launch_bounds__(256) void scan_partials_kernel(
    const int* __restrict__ count, int* __restrict__ partial, int n)
{
    __shared__ int sm[256];
    const int start = blockIdx.x * SCAN_CHUNK;
    int s = 0;
    for (int i = threadIdx.x; i < SCAN_CHUNK; i += 256) {
        int g = start + i;
        if (g < n) s += count[g];
    }
    sm[threadIdx.x] = s;
    __syncthreads();
    for (int off = 128; off > 0; off >>= 1) {
        if (threadIdx.x < off) sm[threadIdx.x] += sm[threadIdx.x + off];
        __syncthreads();
    }
    if (threadIdx.x == 0) partial[blockIdx.x] = sm[0];
}

__global__ void scan_chunkbase_kernel(int* __restrict__ partial,
                                      int* __restrict__ base,
                                      int nchunks, int n)
{
    if (threadIdx.x == 0 && blockIdx.x == 0) {
        int run = 0;
        for (int k = 0; k < nchunks; ++k) {
            int t = partial[k];
            partial[k] = run;
            run += t;
        }
        base[n] = run;
    }
}

__global__ __launch_bounds__(1024) void scan_apply_kernel(
    const int* __restrict__ count, const int* __restrict__ chunk_base,
    int* __restrict__ base, int* __restrict__ cursor, int n)
{
    __shared__ int sm[SCAN_CHUNK];
    const int t = threadIdx.x;
    const int i = blockIdx.x * SCAN_CHUNK + t;
    int v = (i < n) ? count[i] : 0;
    sm[t] = v;
    __syncthreads();
    for (int off = 1; off < SCAN_CHUNK; off <<= 1) {
        int tmp = (t >= off) ? sm[t - off] : 0;
        __syncthreads();
        sm[t] += tmp;
        __syncthreads();
    }
    if (i < n) {
        int excl = sm[t] - v + chunk_base[blockIdx.x];
        base[i] = excl;
        cursor[i] = excl;
    }
}

// also records the owner atom of each perm slot (sequential-read later)
__global__ __launch_bounds__(256) void fill_perm_kernel(
    const int* __restrict__ idx, int* __restrict__ cursor,
    int* __restrict__ perm, int* __restrict__ own, int E)
{
    int e = blockIdx.x * blockDim.x + threadIdx.x;
    if (e < E) {
        int a = idx[e];
        int pos = atomicAdd(&cursor[a], 1);
        perm[pos] = e;
        own[pos] = a;
    }
}

// ---------------------------------------------------------------------------
// Gather kernel v10: round-10 structure with the barrier drain removed.
//  * One 128-thread block (thread = channel) per 128-edge slab; cooperative
//    rbf staging to LDS (ping-pong) + x double-buffered in registers.
//  * KEY CHANGE vs r10: the per-stage __syncthreads() (which compiles to
//    s_waitcnt vmcnt(0) lgkmcnt(0); s_barrier — draining ALL in-flight
//    global loads every stage) is replaced by:
//        ds_write(next) ; s_waitcnt lgkmcnt(0) ; sched_barrier(0) ; s_barrier
//    Raw s_barrier carries no implicit vmcnt drain, so the 37 VMEM loads
//    issued for stage ss+1 stay in flight across the barrier and complete
//    under a counted vmcnt at first use in stage ss+1.  LDS visibility is
//    guaranteed by the explicit lgkmcnt(0) before the barrier.
//  * Segmented flush-on-owner-change; atomics only at slab boundaries.
// ---------------------------------------------------------------------------
__global__ __launch_bounds__(128, 2) void gather_kernel(
    const float* __restrict__ x,       // [E][C]
    const float* __restrict__ rbf,     // [E][RBFD]
    const float* __restrict__ env,     // [E]
    const int*   __restrict__ perm,    // [E]
    const int*   __restrict__ own,     // [E]
    const float* __restrict__ Wrbf,    // [C][RBFD]
    const float* __restrict__ brbf,    // [C]
    float* __restrict__ acc)           // [N][C] (pre-zeroed)
{
    __shared__ int   e_s[SLAB];
    __shared__ float env_s[SLAB];
    __shared__ int   own_s[SLAB];
    __shared__ float rbf_s[2][SS][RBFD];   // 2 x 2560 B, rows 16B-aligned

    const int tid = threadIdx.x;      // 0..127, = channel
    const int p0  = blockIdx.x * SLAB;

    {   // SLAB == blockDim.x: one staging pass, fully coalesced perm/own
        const int e = perm[p0 + tid];
        e_s[tid]   = e;
        env_s[tid] = env[e];
        own_s[tid] = own[p0 + tid];
    }

    float w[RBFD];
#pragma unroll
    for (int r = 0; r < RBFD; ++r) w[r] = Wrbf[tid * RBFD + r];
    const float bias = brbf[tid];

    __syncthreads();   // once, before the pipeline: meta + w complete

    const int first_own = own_s[0];
    int   cur_own = first_own;
    float sum = 0.0f;

#define FLUSH()                                                                \
    do {                                                                       \
        if (cur_own == first_own)                                              \
            unsafeAtomicAdd(&acc[(size_t)cur_own * C + tid], sum);             \
        else acc[(size_t)cur_own * C + tid] = sum;                             \
    } while (0)

    float xr[2][SS];   // x double-buffer (fully unrolled -> registers)
    float st[5];       // rbf staging registers

    // ---- prologue: stage sub-slab 0 (full drain once) ----
#pragma unroll
    for (int p = 0; p < 5; ++p) {
        const int g = p * 128 + tid;            // 0..639
        st[p] = rbf[(size_t)e_s[g / RBFD] * RBFD + (g % RBFD)];
    }
#pragma unroll
    for (int i = 0; i < SS; ++i)
        xr[0][i] = x[(size_t)e_s[i] * C + tid];
    __builtin_amdgcn_sched_barrier(0);
#pragma unroll
    for (int p = 0; p < 5; ++p) {
        const int g = p * 128 + tid;
        rbf_s[0][g / RBFD][g % RBFD] = st[p];
    }
    __syncthreads();

#pragma unroll
    for (int ss = 0; ss < NSS; ++ss) {
        const int sbase = ss * SS;
        const int cur   = ss & 1;

        // ---- issue next sub-slab's loads (rbf -> regs, x -> regs) ----
        if (ss + 1 < NSS) {
#pragma unroll
            for (int p = 0; p < 5; ++p) {
                const int g = p * 128 + tid;
                st[p] = rbf[(size_t)e_s[sbase + SS + g / RBFD] * RBFD + (g % RBFD)];
            }
#pragma unroll
            for (int i = 0; i < SS; ++i)
                xr[cur ^ 1][i] = x[(size_t)e_s[sbase + SS + i] * C + tid];
        }
        __builtin_amdgcn_sched_barrier(0);

        // ---- compute current sub-slab (LDS broadcasts + registers only) ----
#pragma unroll
        for (int j = 0; j < SS; ++j) {
            const float4* q = reinterpret_cast<const float4*>(&rbf_s[cur][j][0]);
            const float4 a = q[0], b = q[1], c = q[2], d = q[3], e4 = q[4];
            float f = bias;
            f = fmaf(a.x,  w[0],  f); f = fmaf(a.y,  w[1],  f);
            f = fmaf(a.z,  w[2],  f); f = fmaf(a.w,  w[3],  f);
            f = fmaf(b.x,  w[4],  f); f = fmaf(b.y,  w[5],  f);
            f = fmaf(b.z,  w[6],  f); f = fmaf(b.w,  w[7],  f);
            f = fmaf(c.x,  w[8],  f); f = fmaf(c.y,  w[9],  f);
            f = fmaf(c.z,  w[10], f); f = fmaf(c.w,  w[11], f);
            f = fmaf(d.x,  w[12], f); f = fmaf(d.y,  w[13], f);
            f = fmaf(d.z,  w[14], f); f = fmaf(d.w,  w[15], f);
            f = fmaf(e4.x, w[16], f); f = fmaf(e4.y, w[17], f);
            f = fmaf(e4.z, w[18], f); f = fmaf(e4.w, w[19], f);

            const float v = f * env_s[sbase + j] * xr[cur][j];
            const int   o = own_s[sbase + j];
            if (o != cur_own) { FLUSH(); sum = 0.0f; cur_own = o; }
            sum += v;
        }
        __builtin_amdgcn_sched_barrier(0);

        // ---- write staged rbf to the other LDS buffer, then a barrier that
        //      waits ONLY lgkmcnt (LDS), leaving global loads in flight ----
        if (ss + 1 < NSS) {
#pragma unroll
            for (int p = 0; p < 5; ++p) {
                const int g = p * 128 + tid;
                rbf_s[cur ^ 1][g / RBFD][g % RBFD] = st[p];
            }
            asm volatile("s_waitcnt lgkmcnt(0)" ::: "memory");
            __builtin_amdgcn_sched_barrier(0);
            __builtin_amdgcn_s_barrier();
        }
    }
    // final flush: cur_own may span into next slab -> atomic
    unsafeAtomicAdd(&acc[(size_t)cur_own * C + tid], sum);
#undef FLUSH
}

// ---------------------------------------------------------------------------
// Fused MLP head (unchanged).
// ---------------------------------------------------------------------------
__device__ __forceinline__ float silu_f(float v) {
    return v * (1.0f / (1.0f + __expf(-v)));
}

__global__ __launch_bounds__(256) void mlp_head_kernel(
    const float* __restrict__ acc,   // [N][C]
    const float* __restrict__ W1T,   // [C][C]  (k-major)
    const float* __restrict__ b1,    // [C]
    const float* __restrict__ W2T,   // [C][C]
    const float* __restrict__ b2,    // [C]
    const float* __restrict__ W3,    // [1][C]
    const float* __restrict__ b3,    // [1]
    float* __restrict__ out,         // [N]
    int natoms)
{
    __shared__ float As[C][C + 1];

    const int tid = threadIdx.x;
    const int a0  = blockIdx.x * C;
    const int tc  = tid & 15;
    const int ta  = tid >> 4;
    const int abase = ta * 8;
    const int cbase = tc * 8;

    {
        const int sub = tid >> 7;
        const int k   = tid & 127;
        for (int pair = 0; pair < 64; ++pair) {
            const int al = pair * 2 + sub;
            const int a  = a0 + al;
            float v = (a < natoms) ? acc[(size_t)a * C + k] : 0.0f;
            As[k][al] = v;
        }
    }
    __syncthreads();

    float r[8][8];

    // layer 1
#pragma unroll
    for (int i = 0; i < 8; ++i)
#pragma unroll
        for (int j = 0; j < 8; ++j) r[i][j] = 0.0f;

#pragma unroll 2
    for (int k = 0; k < C; ++k) {
        float4 bq0 = *reinterpret_cast<const float4*>(W1T + k * C + cbase);
        float4 bq1 = *reinterpret_cast<const float4*>(W1T + k * C + cbase + 4);
        float bv[8] = {bq0.x, bq0.y, bq0.z, bq0.w, bq1.x, bq1.y, bq1.z, bq1.w};
        float av[8];
#pragma unroll
        for (int i = 0; i < 8; ++i) av[i] = As[k][abase + i];
#pragma unroll
        for (int i = 0; i < 8; ++i)
#pragma unroll
            for (int j = 0; j < 8; ++j) r[i][j] = fmaf(av[i], bv[j], r[i][j]);
    }

    __syncthreads();
    {
        float bb[8];
#pragma unroll
        for (int j = 0; j < 8; ++j) bb[j] = b1[cbase + j];
#pragma unroll
        for (int i = 0; i < 8; ++i)
#pragma unroll
            for (int j = 0; j < 8; ++j)
                As[cbase + j][abase + i] = silu_f(r[i][j] + bb[j]);
    }
    __syncthreads();

    // layer 2
#pragma unroll
    for (int i = 0; i < 8; ++i)
#pragma unroll
        for (int j = 0; j < 8; ++j) r[i][j] = 0.0f;

#pragma unroll 2
    for (int k = 0; k < C; ++k) {
        float4 bq0 = *reinterpret_cast<const float4*>(W2T + k * C + cbase);
        float4 bq1 = *reinterpret_cast<const float4*>(W2T + k * C + cbase + 4);
        float bv[8] = {bq0.x, bq0.y, bq0.z, bq0.w, bq1.x, bq1.y, bq1.z, bq1.w};
        float av[8];
#pragma unroll
        for (int i = 0; i < 8; ++i) av[i] = As[k][abase + i];
#pragma unroll
        for (int i = 0; i < 8; ++i)
#pragma unroll
            for (int j = 0; j < 8; ++j) r[i][j] = fmaf(av[i], bv[j], r[i][j]);
    }

    __syncthreads();

    // final: silu(.. + b2) . W3
    {
        float bb[8], w3v[8];
#pragma unroll
        for (int j = 0; j < 8; ++j) bb[j] = b2[cbase + j];
        float4 wq0 = *reinterpret_cast<const float4*>(W3 + cbase);
        float4 wq1 = *reinterpret_cast<const float4*>(W3 + cbase + 4);
        w3v[0]=wq0.x; w3v[1]=wq0.y; w3v[2]=wq0.z; w3v[3]=wq0.w;
        w3v[4]=wq1.x; w3v[5]=wq1.y; w3v[6]=wq1.z; w3v[7]=wq1.w;

#pragma unroll
        for (int i = 0; i < 8; ++i) {
            float p = 0.0f;
#pragma unroll
            for (int j = 0; j < 8; ++j)
                p = fmaf(silu_f(r[i][j] + bb[j]), w3v[j], p);
            As[abase + i][tc] = p;
        }
    }
    __syncthreads();

    if (tid < C) {
        const int a = a0 + tid;
        if (a < natoms) {
            float s = 0.0f;
#pragma unroll
            for (int t = 0; t < 16; ++t) s += As[tid][t];
            out[a] = s + b3[0];
        }
    }
}

// ---------------------------------------------------------------------------
extern "C" void kernel_launch(void* const* d_in, const int* in_sizes, int n_in,
                              void* d_out, int out_size, void* d_ws, size_t ws_size,
                              hipStream_t stream) {
    const float* x      = (const float*)d_in[0];
    const float* rbf    = (const float*)d_in[1];
    const float* env    = (const float*)d_in[2];
    const int*   idx    = (const int*)  d_in[3];
    const float* Wrbf   = (const float*)d_in[5];
    const float* brbf   = (const float*)d_in[6];
    const float* W1     = (const float*)d_in[7];
    const float* b1     = (const float*)d_in[8];
    const float* W2     = (const float*)d_in[9];
    const float* b2     = (const float*)d_in[10];
    const float* W3     = (const float*)d_in[11];
    const float* b3     = (const float*)d_in[12];
    float*       out    = (float*)d_out;

    const int E = in_sizes[0] / C;        // 800000
    const int N = NATOMS;                 // 50000
    const int nchunks = (N + SCAN_CHUNK - 1) / SCAN_CHUNK;   // 49

    // workspace layout
    float* acc     = (float*)d_ws;                    // N*C
    float* W1T     = acc + (size_t)N * C;             // C*C
    float* W2T     = W1T + C * C;                     // C*C
    int*   count   = (int*)(W2T + C * C);             // N
    int*   base    = count + N;                       // N+1
    int*   cursor  = base + (N + 1);                  // N
    int*   partial = cursor + N;                      // 64
    int*   perm    = partial + 64;                    // E
    int*   own     = perm + E;                        // E

    // setup: transpose weights + zero counters + zero acc
    setup_kernel<<<2048, 256, 0, stream>>>(W1, W2, W1T, W2T, count,
                                           (float4*)acc, N, (N * C) / 4);

    histogram_kernel<<<(E + 255) / 256, 256, 0, stream>>>(idx, count, E);
    scan_partials_kernel<<<nchunks, 256, 0, stream>>>(count, partial, N);
    scan_chunkbase_kernel<<<1, 64, 0, stream>>>(partial, base, nchunks, N);
    scan_apply_kernel<<<nchunks, SCAN_CHUNK, 0, stream>>>(count, partial, base, cursor, N);
    fill_perm_kernel<<<(E + 255) / 256, 256, 0, stream>>>(idx, cursor, perm, own, E);

    // gather: one 128-thread block per 128-edge slab
    gather_kernel<<<E / SLAB, 128, 0, stream>>>(x, rbf, env, perm, own,
                                                Wrbf, brbf, acc);

    const int tiles = (N + C - 1) / C;
    mlp_head_kernel<<<tiles, 256, 0, stream>>>(acc, W1T, b1, W2T, b2, W3, b3, out, N);
}